// Round 4
// baseline (3180.426 us; speedup 1.0000x reference)
//
#include <hip/hip_runtime.h>
#include <math.h>

// GRU: T=512, B=64, H=512, L=2. Single persistent fused kernel.
// Round-4 re-tiling: 4 independent batch-groups x 32 blocks
// (16 col-blocks x 2 layers), layer-1 lagging one step. Each block owns
// 32 hidden cols x 16 batches. Gate rows: row = c*4 + q, q={r,z,nx,nh};
// X-image rows {Wir,Wiz,Win,0}, H-image rows {Whr,Whz,0,Whn}.
// Wave wv: Kh = wv&1 (K half), mh = (wv>>1)&1 (M half, 4 Mtiles),
// img = wv>>2 (0=X-dot, 1=H-dot). A-frags resident in registers
// (4 Mtiles x 8 Ksteps = 128 regs); B single N-tile (group's 16 batches).
// Kh halves reduced in LDS (staged +=), X/H summed in epilogue.
//
// Why: previous design (8 cols x 64 batches/block) loaded 128KB of
// B-fragments per block per step (per-CU drain ~2000cy) and pushed
// 12MB/step through the coherent fabric, with a 128-wide grid barrier.
// This tiling halves per-block load bytes (64KB), halves fabric volume
// (6MB/step), and scopes the barrier to 32 blocks per group (groups are
// fully independent: group g's h is only ever read by group g's blocks).
// Sync mechanism itself unchanged (proven): monotone atomic tree
// (2 leaves x 16 + root 2 + gen word) with s_sleep poll, per group.

typedef short bf16x8 __attribute__((ext_vector_type(8)));
typedef float f32x4 __attribute__((ext_vector_type(4)));

__device__ __forceinline__ unsigned short f2bf(float f) {
  unsigned u = __builtin_bit_cast(unsigned, f);
  return (unsigned short)((u + 0x7fff + ((u >> 16) & 1)) >> 16);
}
__device__ __forceinline__ unsigned long long ldq(const unsigned long long* p) {
  return __hip_atomic_load(p, __ATOMIC_RELAXED, __HIP_MEMORY_SCOPE_AGENT);
}
__device__ __forceinline__ void stq(unsigned long long* p,
                                    unsigned long long v) {
  __hip_atomic_store(p, v, __ATOMIC_RELAXED, __HIP_MEMORY_SCOPE_AGENT);
}

// fragment layout within one (t|slot, group) slab of 16KB (8192 shorts):
// element (k, b) -> chunk = (k>>5)*64 + ((k>>3)&3)*16 + (b&15), elem = k&7.
// (b is the batch WITHIN the group's 16-batch tile.)

// per-group barrier lines (words): gb+0 leaf0, gb+16 leaf1, gb+32 root,
// gb+48 gen. All monotone; zeroed by prep each launch.
__device__ __forceinline__ void group_barrier(unsigned* gb, int sub,
                                              unsigned target) {
  __syncthreads();  // drains vmcnt(0): sc1 stores globally visible
  if (threadIdx.x == 0) {
    unsigned prev = __hip_atomic_fetch_add(gb + (sub >> 4) * 16, 1u,
                                           __ATOMIC_RELAXED,
                                           __HIP_MEMORY_SCOPE_AGENT);
    bool done = false;
    if ((prev & 15u) == 15u) {  // 16 blocks per leaf
      unsigned p2 = __hip_atomic_fetch_add(gb + 32, 1u, __ATOMIC_RELAXED,
                                           __HIP_MEMORY_SCOPE_AGENT);
      if ((p2 & 1u) == 1u) {  // 2 leaves
        __hip_atomic_store(gb + 48, target, __ATOMIC_RELAXED,
                           __HIP_MEMORY_SCOPE_AGENT);
        done = true;
      }
    }
    if (!done) {
      while (__hip_atomic_load(gb + 48, __ATOMIC_RELAXED,
                               __HIP_MEMORY_SCOPE_AGENT) < target) {
        __builtin_amdgcn_s_sleep(1);
      }
    }
  }
  __syncthreads();
}

// ---------------------------------------------------------------- prep
// h0buf[g][0] / h1buf[g][0] <- bf16(init) fragment order; zero barrier.
// grid 128x512.
__global__ void gru_prep_h(const float* __restrict__ init,
                           unsigned short* __restrict__ h0buf,
                           unsigned short* __restrict__ h1buf,
                           unsigned* __restrict__ bar) {
  int l = blockIdx.x >> 6;
  int idx = (blockIdx.x & 63) * 512 + threadIdx.x;  // 0..32767
  int k = idx >> 6, b = idx & 63;
  unsigned short v = f2bf(init[(size_t)l * 32768 + b * 512 + k]);
  int g = b >> 4;
  int chunk = (k >> 5) * 64 + ((k >> 3) & 3) * 16 + (b & 15);
  unsigned short* dst = (l == 0) ? h0buf : h1buf;
  dst[(size_t)(g * 2) * 8192 + chunk * 8 + (k & 7)] = v;
  if (blockIdx.x == 0 && threadIdx.x < 512) bar[threadIdx.x] = 0u;
}

// ---------------------------------------------------------------- x transpose
// xbf[(t*4+g)*8192 + chunk*8 + e] = bf16(x[t][b][k]), per-group fragment
// order. grid 512(t) x 512.
__global__ void gru_xprep(const float* __restrict__ x,
                          unsigned short* __restrict__ xbf) {
  int t = blockIdx.x;
#pragma unroll
  for (int it = 0; it < 8; ++it) {
    int ck = it * 512 + threadIdx.x;  // 0..4095
    int b = ck >> 6, kc = ck & 63;    // kc = k>>3
    int g = b >> 4;
    int chunk = (kc >> 2) * 64 + (kc & 3) * 16 + (b & 15);
    const float* src = x + ((size_t)t * 64 + b) * 512 + kc * 8;
    float4 v0 = *(const float4*)(src);
    float4 v1 = *(const float4*)(src + 4);
    unsigned short o[8] = {f2bf(v0.x), f2bf(v0.y), f2bf(v0.z), f2bf(v0.w),
                           f2bf(v1.x), f2bf(v1.y), f2bf(v1.z), f2bf(v1.w)};
    *(uint4*)(xbf + ((size_t)t * 4 + g) * 8192 + chunk * 8) =
        *(const uint4*)o;
  }
}

// ---------------------------------------------------------------- weight images
// wX/wH[l][cb][row][k] bf16, row = c*4+q (c in [0,32)), col = cb*32+c.
// wX rows: q={Wir,Wiz,Win,0}; wH rows: q={Whr,Whz,0,Whn}. grid 128 x 256:
// block = (l, cb, q).
__global__ void gru_wimg(const float* __restrict__ Wir,
                         const float* __restrict__ Wiz,
                         const float* __restrict__ Win,
                         const float* __restrict__ Whr,
                         const float* __restrict__ Whz,
                         const float* __restrict__ Whn,
                         unsigned short* __restrict__ wX,
                         unsigned short* __restrict__ wH) {
  int l = blockIdx.x >> 6, sub = blockIdx.x & 63;
  int cb = sub >> 2, q = sub & 3;
  size_t base = ((size_t)l * 16 + cb) * 128 * 512;
  size_t wbase = (size_t)l * 512 * 512;
  for (int idx = threadIdx.x; idx < 16384; idx += 256) {
    int k = idx >> 5, c = idx & 31;
    int col = cb * 32 + c;
    int row = c * 4 + q;
    size_t we = wbase + (size_t)k * 512 + col;
    float vx = 0.f, vh = 0.f;
    if (q == 0) { vx = Wir[we]; vh = Whr[we]; }
    else if (q == 1) { vx = Wiz[we]; vh = Whz[we]; }
    else if (q == 2) { vx = Win[we]; }
    else { vh = Whn[we]; }
    wX[base + (size_t)row * 512 + k] = f2bf(vx);
    wH[base + (size_t)row * 512 + k] = f2bf(vh);
  }
}

// ---------------------------------------------------------------- fused recurrence
// 128 blocks x 512 threads. g = blk>>5 (batch-group), sub = blk&31,
// role = sub>>4 (0: layer0, 1: layer1 lag-1), blk = sub&15 (col-block,
// cols [blk*32, blk*32+32), batches [g*16, g*16+16)).
__global__ __launch_bounds__(512, 1) void gru_recur_fused(
    const unsigned short* __restrict__ xbf,  // [512][4][8192]
    const unsigned short* __restrict__ wX,   // [2][16][128][512]
    const unsigned short* __restrict__ wH,
    const float* __restrict__ bir, const float* __restrict__ bhr,
    const float* __restrict__ biz, const float* __restrict__ bhz,
    const float* __restrict__ bin_, const float* __restrict__ bhn,
    const float* __restrict__ init,  // [2][64][512]
    unsigned short* h0buf,  // [4 groups][2 slots][8192]
    unsigned short* h1buf,  // [4 groups][2 slots][8192]
    float* __restrict__ Yout, float* __restrict__ finals, unsigned* bar) {
  __shared__ float ghp[2][128][17];         // [img][row][b] (Kh-summed)
  __shared__ unsigned short hpack[64 * 8];  // fragment-order publish staging
  const int tid = threadIdx.x;
  const int lane = tid & 63;
  const int wv = tid >> 6;  // 0..7
  const int Kh = wv & 1, mh = (wv >> 1) & 1, img = wv >> 2;
  const int quad = lane >> 4, mm = lane & 15;
  const int g = blockIdx.x >> 5;
  const int sub = blockIdx.x & 31;
  const int role = sub >> 4;  // block-uniform
  const int blk = sub & 15;
  // epilogue ownership: thread -> (col-in-block ec, batch-in-tile eb)
  const int eb = tid & 15, ec = tid >> 4;  // ec in [0,32)
  const int cg = blk * 32 + ec;            // global col
  const int bbg = g * 16 + eb;             // global batch
  const float bR = bir[role * 512 + cg] + bhr[role * 512 + cg];
  const float bZ = biz[role * 512 + cg] + bhz[role * 512 + cg];
  const float bNX = bin_[role * 512 + cg];
  const float bNH = bhn[role * 512 + cg];
  unsigned* gb = bar + g * 64;

  // ---- A-fragments: this wave's image, 4 Mtiles x 8 Ksteps (128 VGPRs)
  bf16x8 a[4][8];
  {
    const unsigned short* wIb =
        (img == 0 ? wX : wH) + ((size_t)role * 16 + blk) * 65536;
#pragma unroll
    for (int mt = 0; mt < 4; ++mt)
#pragma unroll
      for (int j = 0; j < 8; ++j) {
        int row = mh * 64 + mt * 16 + mm;
        int ko = (Kh * 8 + j) * 32 + quad * 8;
        a[mt][j] = *(const bf16x8*)(wIb + (size_t)row * 512 + ko);
      }
  }
  float hp = init[(size_t)role * 32768 + (size_t)bbg * 512 + cg];

  for (int s = 0; s <= 512; ++s) {
    const bool active = (role == 0) ? (s < 512) : (s >= 1);
    if (active) {
      const int t = (role == 0) ? s : s - 1;
      // B source for THIS wave (wave-uniform): L0: img0=x, img1=h0;
      // L1: img0=h0 (layer-0 output), img1=h1.
      const unsigned long long* Bq;
      bool atomicB;
      if (role == 0) {
        if (img == 0) {
          Bq = (const unsigned long long*)(xbf + ((size_t)t * 4 + g) * 8192);
          atomicB = false;
        } else {
          Bq = (const unsigned long long*)(h0buf +
                                           ((size_t)g * 2 + (s & 1)) * 8192);
          atomicB = true;
        }
      } else {
        if (img == 0) {
          Bq = (const unsigned long long*)(h0buf +
                                           ((size_t)g * 2 + (s & 1)) * 8192);
        } else {
          Bq = (const unsigned long long*)(h1buf +
                                           ((size_t)g * 2 + (t & 1)) * 8192);
        }
        atomicB = true;
      }
      unsigned short* Hdst =
          (role == 0) ? (h0buf + ((size_t)g * 2 + ((s + 1) & 1)) * 8192)
                      : (h1buf + ((size_t)g * 2 + ((t + 1) & 1)) * 8192);
      // ---- B-fragment loads: 8 Ksteps x 16B, all in flight together
      unsigned long long bq[16];
#pragma unroll
      for (int j = 0; j < 8; ++j) {
        int base = ((Kh * 8 + j) * 64 + lane) << 1;  // 8B units
        if (atomicB) {
          bq[2 * j] = ldq(Bq + base);
          bq[2 * j + 1] = ldq(Bq + base + 1);
        } else {
          bq[2 * j] = Bq[base];
          bq[2 * j + 1] = Bq[base + 1];
        }
      }
      // ---- MFMA: 4 Mtiles x 8 Ksteps, 4 independent 8-deep chains
      f32x4 acc[4];
#pragma unroll
      for (int mt = 0; mt < 4; ++mt) acc[mt] = {0.f, 0.f, 0.f, 0.f};
#pragma unroll
      for (int j = 0; j < 8; ++j) {
        union { unsigned long long q[2]; bf16x8 v; } ub;
        ub.q[0] = bq[2 * j];
        ub.q[1] = bq[2 * j + 1];
#pragma unroll
        for (int mt = 0; mt < 4; ++mt)
          acc[mt] =
              __builtin_amdgcn_mfma_f32_16x16x32_bf16(a[mt][j], ub.v, acc[mt],
                                                      0, 0, 0);
      }
      // ---- D -> LDS, Kh staged reduce (C/D: col=lane&15, row=quad*4+reg)
      if (Kh == 0) {
#pragma unroll
        for (int mt = 0; mt < 4; ++mt)
#pragma unroll
          for (int r = 0; r < 4; ++r)
            ghp[img][mh * 64 + mt * 16 + quad * 4 + r][mm] = acc[mt][r];
      }
      __syncthreads();
      if (Kh == 1) {
#pragma unroll
        for (int mt = 0; mt < 4; ++mt)
#pragma unroll
          for (int r = 0; r < 4; ++r)
            ghp[img][mh * 64 + mt * 16 + quad * 4 + r][mm] += acc[mt][r];
      }
      __syncthreads();
      // ---- epilogue: thread owns (col ec, batch eb)
      {
        float gr = ghp[0][ec * 4 + 0][eb] + ghp[1][ec * 4 + 0][eb];
        float gz = ghp[0][ec * 4 + 1][eb] + ghp[1][ec * 4 + 1][eb];
        float gnx = ghp[0][ec * 4 + 2][eb] + ghp[1][ec * 4 + 2][eb];
        float gnh = ghp[0][ec * 4 + 3][eb] + ghp[1][ec * 4 + 3][eb];
        float r = 1.0f / (1.0f + expf(-(gr + bR)));
        float z = 1.0f / (1.0f + expf(-(gz + bZ)));
        float n = tanhf(gnx + bNX + r * (gnh + bNH));
        float hnew = (1.0f - z) * n + z * hp;
        hp = hnew;
        hpack[(((ec >> 3) & 3) * 16 + eb) * 8 + (ec & 7)] = f2bf(hnew);
        if (role == 1) {
          Yout[((size_t)t * 64 + bbg) * 512 + cg] = hnew;
          if (t == 511) finals[32768 + (size_t)bbg * 512 + cg] = hnew;
        } else if (t == 511) {
          finals[(size_t)bbg * 512 + cg] = hnew;
        }
      }
      __syncthreads();
      // ---- publish new h (fragment order), wave 0: this block owns
      // Kstep = blk of its group's slab -> one contiguous 1KB chunk.
      if (wv == 0) {
        const unsigned long long* src =
            (const unsigned long long*)(hpack + lane * 8);
        unsigned long long* dst =
            (unsigned long long*)(Hdst + ((size_t)blk * 64 + lane) * 8);
        stq(dst, src[0]);
        stq(dst + 1, src[1]);
      }
    }
    group_barrier(gb, sub, (unsigned)(s + 1));
  }
}

// ---------------------------------------------------------------- launch
extern "C" void kernel_launch(void* const* d_in, const int* in_sizes, int n_in,
                              void* d_out, int out_size, void* d_ws,
                              size_t ws_size, hipStream_t stream) {
  const float* x = (const float*)d_in[0];
  const float* init = (const float*)d_in[1];
  const float* w_ir = (const float*)d_in[2];
  const float* w_hr = (const float*)d_in[3];
  const float* w_iz = (const float*)d_in[4];
  const float* w_hz = (const float*)d_in[5];
  const float* w_in_ = (const float*)d_in[6];
  const float* w_hn = (const float*)d_in[7];
  const float* b_ir = (const float*)d_in[8];
  const float* b_hr = (const float*)d_in[9];
  const float* b_iz = (const float*)d_in[10];
  const float* b_hz = (const float*)d_in[11];
  const float* b_in_ = (const float*)d_in[12];
  const float* b_hn = (const float*)d_in[13];
  float* out = (float*)d_out;
  float* Y = out;                                // [T,B,H] = layer-1 outputs
  float* finals = out + (size_t)512 * 64 * 512;  // [L,B,H]

  // workspace layout (ushorts unless noted)
  unsigned short* xbf = (unsigned short*)d_ws;            // 512*4*8192
  unsigned short* wX = xbf + (size_t)512 * 32768;         // 2*16*128*512
  unsigned short* wH = wX + (size_t)2 * 16 * 128 * 512;
  unsigned short* h0buf = wH + (size_t)2 * 16 * 128 * 512;  // 4*2*8192
  unsigned short* h1buf = h0buf + (size_t)4 * 2 * 8192;     // 4*2*8192
  unsigned* bar = (unsigned*)(h1buf + (size_t)4 * 2 * 8192);  // 512 words

  gru_prep_h<<<128, 512, 0, stream>>>(init, h0buf, h1buf, bar);
  gru_xprep<<<512, 512, 0, stream>>>(x, xbf);
  gru_wimg<<<128, 256, 0, stream>>>(w_ir, w_iz, w_in_, w_hr, w_hz, w_hn, wX,
                                    wH);
  gru_recur_fused<<<128, 512, 0, stream>>>(
      xbf, wX, wH, b_ir, b_hr, b_iz, b_hz, b_in_, b_hn, init, h0buf, h1buf, Y,
      finals, bar);
}

// Round 5
// 3067.899 us; speedup vs baseline: 1.0367x; 1.0367x over previous
//
#include <hip/hip_runtime.h>
#include <math.h>

// GRU: T=512, B=64, H=512, L=2. Single persistent fused kernel:
// 128 blocks = 64 layer-0 + 64 layer-1, layer-1 lagging one step (wavefront
// pipeline), 513 steps. Each block owns 8 hidden cols; 32 gate-rows = 8 cols
// x {r, z, n_x, n_h}. X-projection and H-dot are both MFMA (bf16), split X/H
// accumulators summed in the epilogue. Layer-0 X input = pre-transposed bf16
// x (cached loads, pre-issued BEFORE the flag wait); layer-1 X input =
// layer-0's published bf16 h (sc1 loads). h exchanged via relaxed agent-scope
// (sc1) 8B atomics in MFMA B-fragment order. Compute core identical to the
// proven 2.5ms kernel.
//
// Round-5 sync: minimum-hop flags. Evidence: tree barrier = 5 serial
// coherent hops (drain, leaf RMW, root RMW, gen store, poll) at ~1.5k cy
// each ~= 7.5k cy of the 11.7k cy step. Flags = 3 hops (drain, flag store,
// detect). Rounds 1/2 failed from hot polling (poll reads queue ahead of
// producer stores on the flag lines), so:
//  - eager first check (steady-state: already satisfied, zero traffic)
//  - straggler-masked re-poll (only lanes with a lagging flag re-issue)
//  - s_sleep(1) backoff between rounds
//  - flags padded to 64B stride (one poll lane per cache line)
// Conditions (verified R1 semantics, h0 ring 4-deep, h1 ring 2-deep):
//   role 0 step s: flags0 >= s && flags1 >= s-2
//   role 1 step s: flags0 >= s && flags1 >= s
// Overwrite safety: h0 slot (s+1)&3 collides only with layer-1 step s+1
// (waits flags0 >= s+1) and layer-0 peers below step s (excluded by
// flags0 >= s); h1 2-ring is safe under the within-layer spread<=1 that the
// flags0/flags1 >= s waits enforce.

typedef short bf16x8 __attribute__((ext_vector_type(8)));
typedef float f32x4 __attribute__((ext_vector_type(4)));

__device__ __forceinline__ unsigned short f2bf(float f) {
  unsigned u = __builtin_bit_cast(unsigned, f);
  return (unsigned short)((u + 0x7fff + ((u >> 16) & 1)) >> 16);
}
__device__ __forceinline__ unsigned long long ldq(const unsigned long long* p) {
  return __hip_atomic_load(p, __ATOMIC_RELAXED, __HIP_MEMORY_SCOPE_AGENT);
}
__device__ __forceinline__ void stq(unsigned long long* p,
                                    unsigned long long v) {
  __hip_atomic_store(p, v, __ATOMIC_RELAXED, __HIP_MEMORY_SCOPE_AGENT);
}
__device__ __forceinline__ void stw(unsigned* p, unsigned v) {
  __hip_atomic_store(p, v, __ATOMIC_RELAXED, __HIP_MEMORY_SCOPE_AGENT);
}

// fragment-order: element (k,b) -> chunk*8 + (k&7)
__device__ __forceinline__ int hchunk(int k, int b) {
  return ((b >> 4) * 16 + (k >> 5)) * 64 + ((k >> 3) & 3) * 16 + (b & 15);
}

// ---------------------------------------------------------------- prep
// h0buf slot0 / h1buf slot0 <- bf16(init) fragment order; zero flags.
// Flags: pair for col-block l at bar[l*16] (layer0) / bar[l*16+1] (layer1),
// 64B stride. grid 128x512.
__global__ void gru_prep_h(const float* __restrict__ init,
                           unsigned short* __restrict__ h0buf,
                           unsigned short* __restrict__ h1buf,
                           unsigned* __restrict__ bar) {
  int l = blockIdx.x >> 6;
  int idx = (blockIdx.x & 63) * 512 + threadIdx.x;  // 0..32767
  int k = idx >> 6, b = idx & 63;
  unsigned short v = f2bf(init[(size_t)l * 32768 + b * 512 + k]);
  unsigned short* dst = (l == 0) ? h0buf : h1buf;
  dst[hchunk(k, b) * 8 + (k & 7)] = v;
  if (blockIdx.x == 0) {
    bar[threadIdx.x] = 0u;
    bar[512 + threadIdx.x] = 0u;
  }
}

// ---------------------------------------------------------------- x transpose
// xbf[t][ck*8+e] = bf16(x[t][b][k]) in fragment order. grid 512(t) x 512.
__global__ void gru_xprep(const float* __restrict__ x,
                          unsigned short* __restrict__ xbf) {
  int t = blockIdx.x;
#pragma unroll
  for (int it = 0; it < 8; ++it) {
    int ck = it * 512 + threadIdx.x;  // 0..4095
    int b = (ck >> 10) * 16 + (ck & 15);
    int k0 = ((ck >> 6) & 15) * 32 + ((ck >> 4) & 3) * 8;
    const float* src = x + ((size_t)t * 64 + b) * 512 + k0;
    float4 v0 = *(const float4*)(src);
    float4 v1 = *(const float4*)(src + 4);
    unsigned short o[8] = {f2bf(v0.x), f2bf(v0.y), f2bf(v0.z), f2bf(v0.w),
                           f2bf(v1.x), f2bf(v1.y), f2bf(v1.z), f2bf(v1.w)};
    *(uint4*)(xbf + (size_t)t * 32768 + ck * 8) = *(const uint4*)o;
  }
}

// ---------------------------------------------------------------- weight images
// wX/wH[l][blk][row][k] bf16, row = c*4+q, col = blk*8+c.
// wX rows: q={Wir,Wiz,Win,0}; wH rows: q={Whr,Whz,0,Whn}. grid 128 x 256.
__global__ void gru_wimg(const float* __restrict__ Wir,
                         const float* __restrict__ Wiz,
                         const float* __restrict__ Win,
                         const float* __restrict__ Whr,
                         const float* __restrict__ Whz,
                         const float* __restrict__ Whn,
                         unsigned short* __restrict__ wX,
                         unsigned short* __restrict__ wH) {
  int l = blockIdx.x >> 6, blk = blockIdx.x & 63;
  size_t base = ((size_t)l * 64 + blk) * 32 * 512;
  size_t wbase = (size_t)l * 512 * 512;
  for (int idx = threadIdx.x; idx < 16384; idx += 256) {
    int c = idx & 7, k = (idx >> 3) & 511, q = idx >> 12;
    int col = blk * 8 + c;
    int row = c * 4 + q;
    size_t we = wbase + (size_t)k * 512 + col;
    float vx = 0.f, vh = 0.f;
    if (q == 0) { vx = Wir[we]; vh = Whr[we]; }
    else if (q == 1) { vx = Wiz[we]; vh = Whz[we]; }
    else if (q == 2) { vx = Win[we]; }
    else { vh = Whn[we]; }
    wX[base + (size_t)row * 512 + k] = f2bf(vx);
    wH[base + (size_t)row * 512 + k] = f2bf(vh);
  }
}

// ---------------------------------------------------------------- fused recurrence
// 128 blocks x 512 threads. role = blk>>6 (0: layer0, 1: layer1 lag-1).
// Wave wv: Nt = wv&3 (16-batch tile), Kh = wv>>2 (K half). A-frags in VGPRs.
__global__ __launch_bounds__(512, 1) void gru_recur_fused(
    const unsigned short* __restrict__ xbf,  // [512][32768]
    const unsigned short* __restrict__ wX,   // [2][64][32][512]
    const unsigned short* __restrict__ wH,
    const float* __restrict__ bir, const float* __restrict__ bhr,
    const float* __restrict__ biz, const float* __restrict__ bhz,
    const float* __restrict__ bin_, const float* __restrict__ bhn,
    const float* __restrict__ init,  // [2][64][512]
    unsigned short* h0buf,  // ring of 4 x 32768
    unsigned short* h1buf,  // ring of 2 x 32768
    float* __restrict__ Yout, float* __restrict__ finals, unsigned* bar) {
  __shared__ float ghp[2][32][66];          // [Kh][row][b]
  __shared__ unsigned short hpack[64 * 8];  // [b][c]
  const int tid = threadIdx.x;
  const int lane = tid & 63;
  const int wv = tid >> 6;  // 0..7
  const int Nt = wv & 3, Kh = wv >> 2;
  const int quad = lane >> 4, mm = lane & 15;
  const int role = blockIdx.x >> 6;  // block-uniform
  const int blk = blockIdx.x & 63;
  const int cg0 = blk * 8;
  const int c = wv, bb = lane;
  const int cg = cg0 + c;
  const float bR = bir[role * 512 + cg] + bhr[role * 512 + cg];
  const float bZ = biz[role * 512 + cg] + bhz[role * 512 + cg];
  const float bNX = bin_[role * 512 + cg];
  const float bNH = bhn[role * 512 + cg];

  // ---- A-fragments: X-image and H-image, 2 Mtiles x 8 Ksteps each
  bf16x8 aX0[8], aX1[8], aH0[8], aH1[8];
  {
    const unsigned short* wXb = wX + ((size_t)role * 64 + blk) * 32 * 512;
    const unsigned short* wHb = wH + ((size_t)role * 64 + blk) * 32 * 512;
#pragma unroll
    for (int j = 0; j < 8; ++j) {
      int ko = (Kh * 8 + j) * 32 + quad * 8;
      aX0[j] = *(const bf16x8*)(wXb + (size_t)mm * 512 + ko);
      aX1[j] = *(const bf16x8*)(wXb + (size_t)(16 + mm) * 512 + ko);
      aH0[j] = *(const bf16x8*)(wHb + (size_t)mm * 512 + ko);
      aH1[j] = *(const bf16x8*)(wHb + (size_t)(16 + mm) * 512 + ko);
    }
  }
  float hp = init[(size_t)role * 32768 + bb * 512 + cg];

  for (int s = 0; s <= 512; ++s) {
    const bool active = (role == 0) ? (s < 512) : (s >= 1);
    if (active) {
      const int t = (role == 0) ? s : s - 1;
      const unsigned long long* Xq =
          (const unsigned long long*)((role == 0)
                                          ? (xbf + (size_t)t * 32768)
                                          : (h0buf + (size_t)(s & 3) * 32768));
      const unsigned long long* Hq =
          (const unsigned long long*)((role == 0)
                                          ? (h0buf + (size_t)(s & 3) * 32768)
                                          : (h1buf + (size_t)(t & 1) * 32768));
      unsigned short* Hdst = (role == 0)
                                 ? (h0buf + (size_t)((s + 1) & 3) * 32768)
                                 : (h1buf + (size_t)((t + 1) & 1) * 32768);
      unsigned long long xq[16], hq[16];
      // ---- layer-0 X loads are static: issue BEFORE the flag wait so
      // their latency overlaps the detect latency.
      if (role == 0) {
#pragma unroll
        for (int j = 0; j < 8; ++j) {
          int base = ((Nt * 16 + Kh * 8 + j) * 64 + lane) << 1;
          xq[2 * j] = Xq[base];
          xq[2 * j + 1] = Xq[base + 1];
        }
        __builtin_amdgcn_sched_barrier(0);  // keep loads issued before poll
      }
      // ---- flag wait: wave 0, lane l owns pair l (64B stride). Eager first
      // check; only unsatisfied lanes re-poll; s_sleep backoff.
      if (wv == 0) {
        const int need0 = s;
        const int need1 = (role == 0) ? s - 2 : s;
        const unsigned long long* fq =
            (const unsigned long long*)bar + (size_t)lane * 8;
        unsigned long long pq = ldq(fq);
        bool ok = ((int)(unsigned)pq >= need0) &&
                  ((int)(unsigned)(pq >> 32) >= need1);
        while (!__all(ok)) {
          __builtin_amdgcn_s_sleep(1);
          if (!ok) {
            pq = ldq(fq);
            ok = ((int)(unsigned)pq >= need0) &&
                 ((int)(unsigned)(pq >> 32) >= need1);
          }
        }
      }
      __syncthreads();
      // ---- B-fragment loads (all independent, in flight together)
#pragma unroll
      for (int j = 0; j < 8; ++j) {
        int base = ((Nt * 16 + Kh * 8 + j) * 64 + lane) << 1;
        if (role == 1) {  // sc1 (published h0)
          xq[2 * j] = ldq(Xq + base);
          xq[2 * j + 1] = ldq(Xq + base + 1);
        }
        hq[2 * j] = ldq(Hq + base);
        hq[2 * j + 1] = ldq(Hq + base + 1);
      }
      // ---- MFMA: split X/H accumulators (halves dependent-chain depth)
      f32x4 a0x = {0.f, 0.f, 0.f, 0.f}, a0h = {0.f, 0.f, 0.f, 0.f};
      f32x4 a1x = {0.f, 0.f, 0.f, 0.f}, a1h = {0.f, 0.f, 0.f, 0.f};
#pragma unroll
      for (int j = 0; j < 8; ++j) {
        union { unsigned long long q[2]; bf16x8 v; } ux, uh;
        ux.q[0] = xq[2 * j]; ux.q[1] = xq[2 * j + 1];
        uh.q[0] = hq[2 * j]; uh.q[1] = hq[2 * j + 1];
        a0x = __builtin_amdgcn_mfma_f32_16x16x32_bf16(aX0[j], ux.v, a0x, 0, 0, 0);
        a1x = __builtin_amdgcn_mfma_f32_16x16x32_bf16(aX1[j], ux.v, a1x, 0, 0, 0);
        a0h = __builtin_amdgcn_mfma_f32_16x16x32_bf16(aH0[j], uh.v, a0h, 0, 0, 0);
        a1h = __builtin_amdgcn_mfma_f32_16x16x32_bf16(aH1[j], uh.v, a1h, 0, 0, 0);
      }
      f32x4 acc0 = a0x + a0h, acc1 = a1x + a1h;
      // ---- D -> LDS (C/D: col=lane&15, row=quad*4+reg)
      {
        float* g = &ghp[Kh][0][0];
        int ncol = Nt * 16 + mm;
#pragma unroll
        for (int r = 0; r < 4; ++r) g[(quad * 4 + r) * 66 + ncol] = acc0[r];
#pragma unroll
        for (int r = 0; r < 4; ++r)
          g[(16 + quad * 4 + r) * 66 + ncol] = acc1[r];
      }
      __syncthreads();
      // ---- epilogue: thread owns (col c, batch bb)
      {
        float gr = ghp[0][c * 4 + 0][bb] + ghp[1][c * 4 + 0][bb];
        float gz = ghp[0][c * 4 + 1][bb] + ghp[1][c * 4 + 1][bb];
        float gnx = ghp[0][c * 4 + 2][bb] + ghp[1][c * 4 + 2][bb];
        float gnh = ghp[0][c * 4 + 3][bb] + ghp[1][c * 4 + 3][bb];
        float r = 1.0f / (1.0f + expf(-(gr + bR)));
        float z = 1.0f / (1.0f + expf(-(gz + bZ)));
        float n = tanhf(gnx + bNX + r * (gnh + bNH));
        float hnew = (1.0f - z) * n + z * hp;
        hp = hnew;
        hpack[bb * 8 + c] = f2bf(hnew);
        if (role == 1) {
          Yout[((size_t)t * 64 + bb) * 512 + cg] = hnew;
          if (t == 511) finals[32768 + bb * 512 + cg] = hnew;
        } else if (t == 511) {
          finals[bb * 512 + cg] = hnew;
        }
      }
      __syncthreads();
      // ---- publish new h (bf16 fragment order), wave 0; drain own stores,
      // then ONE monotone flag store. 3 coherent hops total.
      if (wv == 0) {
        int ck = ((lane >> 4) * 16 + (cg0 >> 5)) * 64 + ((cg0 >> 3) & 3) * 16 +
                 (lane & 15);
        const unsigned long long* src =
            (const unsigned long long*)(hpack + lane * 8);
        unsigned long long* dst = (unsigned long long*)(Hdst + (size_t)ck * 8);
        stq(dst, src[0]);
        stq(dst + 1, src[1]);
        asm volatile("s_waitcnt vmcnt(0)" ::: "memory");
        if (lane == 0) stw(bar + blk * 16 + role, (unsigned)(s + 1));
      }
    } else {
      // inactive edge steps (role1@s=0, role0@s=512) still advance the flag
      if (tid == 0) stw(bar + blk * 16 + role, (unsigned)(s + 1));
    }
  }
}

// ---------------------------------------------------------------- launch
extern "C" void kernel_launch(void* const* d_in, const int* in_sizes, int n_in,
                              void* d_out, int out_size, void* d_ws,
                              size_t ws_size, hipStream_t stream) {
  const float* x = (const float*)d_in[0];
  const float* init = (const float*)d_in[1];
  const float* w_ir = (const float*)d_in[2];
  const float* w_hr = (const float*)d_in[3];
  const float* w_iz = (const float*)d_in[4];
  const float* w_hz = (const float*)d_in[5];
  const float* w_in_ = (const float*)d_in[6];
  const float* w_hn = (const float*)d_in[7];
  const float* b_ir = (const float*)d_in[8];
  const float* b_hr = (const float*)d_in[9];
  const float* b_iz = (const float*)d_in[10];
  const float* b_hz = (const float*)d_in[11];
  const float* b_in_ = (const float*)d_in[12];
  const float* b_hn = (const float*)d_in[13];
  float* out = (float*)d_out;
  float* Y = out;                                // [T,B,H] = layer-1 outputs
  float* finals = out + (size_t)512 * 64 * 512;  // [L,B,H]

  // workspace layout (ushorts unless noted)
  unsigned short* xbf = (unsigned short*)d_ws;            // 512*32768
  unsigned short* wX = xbf + (size_t)512 * 32768;         // 2*64*32*512
  unsigned short* wH = wX + (size_t)2 * 64 * 32 * 512;
  unsigned short* h0buf = wH + (size_t)2 * 64 * 32 * 512; // 4*32768 (ring)
  unsigned short* h1buf = h0buf + (size_t)4 * 32768;      // 2*32768
  unsigned* bar = (unsigned*)(h1buf + 2 * 32768);         // 1024 words (4KB)

  gru_prep_h<<<128, 512, 0, stream>>>(init, h0buf, h1buf, bar);
  gru_xprep<<<512, 512, 0, stream>>>(x, xbf);
  gru_wimg<<<128, 256, 0, stream>>>(w_ir, w_iz, w_in_, w_hr, w_hz, w_hn, wX,
                                    wH);
  gru_recur_fused<<<128, 512, 0, stream>>>(
      xbf, wX, wH, b_ir, b_hr, b_iz, b_hz, b_in_, b_hn, init, h0buf, h1buf, Y,
      finals, bar);
}